// Round 6
// baseline (286.739 us; speedup 1.0000x reference)
//
#include <hip/hip_runtime.h>
#include <math.h>

// Problem constants
#define Bsz 64
#define Nn 512
#define Ff 128
#define Hh 256
#define OUTD 6
#define MTOT (Bsz * Nn)   // 32768

typedef __bf16 bf16x8 __attribute__((ext_vector_type(8)));
typedef float f32x4 __attribute__((ext_vector_type(4)));
typedef int int4v __attribute__((ext_vector_type(4)));
typedef unsigned short ushort4v __attribute__((ext_vector_type(4)));

__device__ __forceinline__ unsigned short f2bf(float f) {
    unsigned u = __float_as_uint(f);
    u += 0x7FFFu + ((u >> 16) & 1u);        // RNE
    return (unsigned short)(u >> 16);
}
__device__ __forceinline__ float bf2f(unsigned short s) {
    return __uint_as_float(((unsigned)s) << 16);
}

// XOR swizzle of the 16B k-chunk within a 64B LDS row (kills ds_read_b128 bank conflicts)
#define SWZ(r) (((r) ^ ((r) >> 2)) & 3)

// async 16B global->LDS (DMA; LDS dest = wave-uniform base + lane*16)
__device__ __forceinline__ void async_ld16(const unsigned short* g, unsigned short* l) {
    __builtin_amdgcn_global_load_lds(
        (const __attribute__((address_space(1))) void*)g,
        (__attribute__((address_space(3))) void*)l,
        16, 0, 0);
}

#define LDH 40   // padded LDS row stride (bf16) for the non-async h0 kernel

// ---------------- bf16 MFMA GEMM, double-buffered, fused second operand pair -------
// out = act( A0@B0 [+ A1@B1] + bias ); B operands TRANSPOSED (BT[n][k]); row stride == K.
// Tile: BMt x 128. Batched via blockIdx.z strides. flags&1 = relu; flags&4 = column-sum
// pool into gpool (no C/CT store). CT (optional) = transposed copy [graph][n][node].
template<int BMt>
__global__ __launch_bounds__(256) void gemm_bf16(
    const unsigned short* __restrict__ A0, const unsigned short* __restrict__ B0T,
    const unsigned short* __restrict__ A1, const unsigned short* __restrict__ B1T,
    const float* __restrict__ bias,
    unsigned short* __restrict__ C, unsigned short* __restrict__ CT,
    float* __restrict__ gpool,
    int M, int Ntot, int K0, int K1,
    long strideA0, long strideB0, long strideC, int flags)
{
    constexpr int IT = BMt / 32;          // acc rows of 16x16 tiles per wave
    constexpr int ATS = BMt * 32;         // A tile shorts
    constexpr int BTS = 128 * 32;         // B tile shorts
    constexpr int G = (BMt + 128) / 16;   // 16-row staging groups per tile

    int bz = blockIdx.z;
    A0 += (long)bz * strideA0;
    B0T += (long)bz * strideB0;
    if (C) C += (long)bz * strideC;

    __shared__ unsigned short As[2 * ATS];   // double-buffered, 64B rows, swizzled chunks
    __shared__ unsigned short Bs[2 * BTS];

    int tid = threadIdx.x;
    int lane = tid & 63;
    int wave = tid >> 6;
    int quad = lane >> 4, l16 = lane & 15;
    int wm = (wave >> 1) * (BMt / 2), wn = (wave & 1) * 64;
    int m0 = blockIdx.x * BMt, n0 = blockIdx.y * 128;

    int sr = lane >> 2;        // staging row within 16-row group
    int sc = lane & 3;         // staging chunk slot

    int T0 = K0 >> 5, T1 = K1 >> 5;
    int T = T0 + T1;

    f32x4 acc[IT][4] = {};

    // issue tile g's staging loads into buffer (g&1)
    auto issue = [&](int g) {
        const unsigned short* Ag; const unsigned short* Bg; int Kg, kk;
        if (g < T0) { Ag = A0; Bg = B0T; Kg = K0; kk = g << 5; }
        else        { Ag = A1; Bg = B1T; Kg = K1; kk = (g - T0) << 5; }
        unsigned short* Ad = As + (g & 1) * ATS;
        unsigned short* Bd = Bs + (g & 1) * BTS;
        #pragma unroll
        for (int gi = 0; gi < G / 4; ++gi) {
            int r0 = (gi * 4 + wave) * 16;
            int r = (r0 < BMt ? r0 : r0 - BMt) + sr;
            int c = sc ^ SWZ(r);
            if (r0 < BMt)
                async_ld16(Ag + (long)(m0 + r) * Kg + kk + c * 8, Ad + (r - sr) * 32);
            else
                async_ld16(Bg + (long)(n0 + r) * Kg + kk + c * 8, Bd + (r - sr) * 32);
        }
    };

    issue(0);
    for (int g = 0; g < T; ++g) {
        __syncthreads();                      // drains tile g's loads (issued last iter)
        if (g + 1 < T) issue(g + 1);          // overlaps with compute of tile g
        const unsigned short* Ab = As + (g & 1) * ATS;
        const unsigned short* Bb = Bs + (g & 1) * BTS;
        bf16x8 af[IT], bfr[4];
        #pragma unroll
        for (int i = 0; i < IT; ++i) {
            int r = wm + i * 16 + l16;
            af[i] = *(const bf16x8*)&Ab[r * 32 + (quad ^ SWZ(r)) * 8];
        }
        #pragma unroll
        for (int j = 0; j < 4; ++j) {
            int r = wn + j * 16 + l16;
            bfr[j] = *(const bf16x8*)&Bb[r * 32 + (quad ^ SWZ(r)) * 8];
        }
        #pragma unroll
        for (int i = 0; i < IT; ++i)
            #pragma unroll
            for (int j = 0; j < 4; ++j)
                acc[i][j] = __builtin_amdgcn_mfma_f32_16x16x32_bf16(
                    af[i], bfr[j], acc[i][j], 0, 0, 0);
    }

    // ---- pooled epilogue (dense layer-2): column sums -> gpool ----
    if (flags & 4) {
        __syncthreads();                       // all frag reads done; reuse As
        float* fs = (float*)As;
        if (tid < 128) fs[tid] = 0.f;
        __syncthreads();
        #pragma unroll
        for (int j = 0; j < 4; ++j) {
            int nl = wn + j * 16 + l16;
            float bv = bias ? bias[n0 + nl] : 0.f;
            float cs = (float)(IT * 4) * bv;   // rows per lane in this column slice
            #pragma unroll
            for (int i = 0; i < IT; ++i) {
                f32x4 v = acc[i][j];
                cs += v[0] + v[1] + v[2] + v[3];
            }
            atomicAdd(&fs[nl], cs);
        }
        __syncthreads();
        if (tid < 128)
            atomicAdd(&gpool[(long)(m0 >> 9) * Hh + n0 + tid], fs[tid]);
        return;
    }

    // ---- normal epilogue. C/D layout: col = lane&15, row = quad*4 + reg ----
    int ldc = Ntot;
    #pragma unroll
    for (int i = 0; i < IT; ++i) {
        int mb = m0 + wm + i * 16 + quad * 4;
        #pragma unroll
        for (int j = 0; j < 4; ++j) {
            int n = n0 + wn + j * 16 + l16;
            f32x4 v = acc[i][j];
            float bv = bias ? bias[n] : 0.0f;
            float o0 = v[0] + bv, o1 = v[1] + bv, o2 = v[2] + bv, o3 = v[3] + bv;
            if (flags & 1) {
                o0 = fmaxf(o0, 0.f); o1 = fmaxf(o1, 0.f);
                o2 = fmaxf(o2, 0.f); o3 = fmaxf(o3, 0.f);
            }
            unsigned short s0 = f2bf(o0), s1 = f2bf(o1), s2 = f2bf(o2), s3 = f2bf(o3);
            if (C) {
                C[(long)(mb + 0) * ldc + n] = s0;
                C[(long)(mb + 1) * ldc + n] = s1;
                C[(long)(mb + 2) * ldc + n] = s2;
                C[(long)(mb + 3) * ldc + n] = s3;
            }
            if (CT) {
                ushort4v p; p[0] = s0; p[1] = s1; p[2] = s2; p[3] = s3;
                long ti = ((long)(mb >> 9) * Ntot + n) * 512 + (mb & 511);
                *(ushort4v*)&CT[ti] = p;
            }
        }
    }
}

// ---------------- h0 = bf16(x) @ WgT + bg  (MFMA; writes h0b + h0T + sq) ------------
__global__ __launch_bounds__(256) void h0_mfma(
    const float* __restrict__ x, const unsigned short* __restrict__ WgT,
    const float* __restrict__ bg,
    unsigned short* __restrict__ h0b, unsigned short* __restrict__ h0T,
    float* __restrict__ sqv)
{
    __shared__ unsigned short As[128 * LDH];
    __shared__ unsigned short Bs[128 * LDH];
    __shared__ float rsq[128];

    int tid = threadIdx.x;
    int lane = tid & 63;
    int wave = tid >> 6;
    int quad = lane >> 4, l16 = lane & 15;
    int wm = (wave >> 1) * 64, wn = (wave & 1) * 64;
    int m0 = blockIdx.x * 128;          // N = 128 (single column block)

    f32x4 acc[4][4] = {};

    for (int k0 = 0; k0 < Ff; k0 += 32) {
        __syncthreads();
        #pragma unroll
        for (int l = 0; l < 2; ++l) {
            int idx = tid + l * 256;
            int r = idx >> 2, ch = idx & 3;
            const float* px = x + (long)(m0 + r) * Ff + k0 + ch * 8;
            float4 xa = *(const float4*)px;
            float4 xb = *(const float4*)(px + 4);
            ushort4v pa, pb;
            pa[0] = f2bf(xa.x); pa[1] = f2bf(xa.y); pa[2] = f2bf(xa.z); pa[3] = f2bf(xa.w);
            pb[0] = f2bf(xb.x); pb[1] = f2bf(xb.y); pb[2] = f2bf(xb.z); pb[3] = f2bf(xb.w);
            *(ushort4v*)&As[r * LDH + ch * 8] = pa;
            *(ushort4v*)&As[r * LDH + ch * 8 + 4] = pb;
            int4v vb = *(const int4v*)(WgT + (long)r * Ff + k0 + ch * 8);
            *(int4v*)&Bs[r * LDH + ch * 8] = vb;
        }
        __syncthreads();
        bf16x8 af[4], bfr[4];
        #pragma unroll
        for (int i = 0; i < 4; ++i)
            af[i] = *(const bf16x8*)&As[(wm + i * 16 + l16) * LDH + quad * 8];
        #pragma unroll
        for (int j = 0; j < 4; ++j)
            bfr[j] = *(const bf16x8*)&Bs[(wn + j * 16 + l16) * LDH + quad * 8];
        #pragma unroll
        for (int i = 0; i < 4; ++i)
            #pragma unroll
            for (int j = 0; j < 4; ++j)
                acc[i][j] = __builtin_amdgcn_mfma_f32_16x16x32_bf16(
                    af[i], bfr[j], acc[i][j], 0, 0, 0);
    }

    if (tid < 128) rsq[tid] = 0.f;
    __syncthreads();

    #pragma unroll
    for (int i = 0; i < 4; ++i) {
        int lrow = wm + i * 16 + quad * 4;   // local row of first of 4
        int mb = m0 + lrow;
        float rp0 = 0.f, rp1 = 0.f, rp2 = 0.f, rp3 = 0.f;
        #pragma unroll
        for (int j = 0; j < 4; ++j) {
            int n = wn + j * 16 + l16;
            f32x4 v = acc[i][j];
            float bv = bg[n];
            unsigned short s0 = f2bf(v[0] + bv), s1 = f2bf(v[1] + bv);
            unsigned short s2 = f2bf(v[2] + bv), s3 = f2bf(v[3] + bv);
            h0b[(long)(mb + 0) * Ff + n] = s0;
            h0b[(long)(mb + 1) * Ff + n] = s1;
            h0b[(long)(mb + 2) * Ff + n] = s2;
            h0b[(long)(mb + 3) * Ff + n] = s3;
            ushort4v p; p[0] = s0; p[1] = s1; p[2] = s2; p[3] = s3;
            long ti = ((long)(mb >> 9) * Ff + n) * 512 + (mb & 511);
            *(ushort4v*)&h0T[ti] = p;
            float f0 = bf2f(s0), f1 = bf2f(s1), f2 = bf2f(s2), f3 = bf2f(s3);
            rp0 += f0 * f0; rp1 += f1 * f1; rp2 += f2 * f2; rp3 += f3 * f3;
        }
        // reduce across the 16 lanes (same quad) covering these 4 rows
        #pragma unroll
        for (int m = 1; m < 16; m <<= 1) {
            rp0 += __shfl_xor(rp0, m);
            rp1 += __shfl_xor(rp1, m);
            rp2 += __shfl_xor(rp2, m);
            rp3 += __shfl_xor(rp3, m);
        }
        if (l16 == 0) {   // two waves share rows -> atomic
            atomicAdd(&rsq[lrow + 0], rp0);
            atomicAdd(&rsq[lrow + 1], rp1);
            atomicAdd(&rsq[lrow + 2], rp2);
            atomicAdd(&rsq[lrow + 3], rp3);
        }
    }
    __syncthreads();
    if (tid < 128) sqv[m0 + tid] = rsq[tid];
}

// ---------------- Gram -> Gaussian adjacency A via MFMA (dbuf async staging) -------
__global__ __launch_bounds__(256) void gram_A_mfma(
    const unsigned short* __restrict__ h0b, const float* __restrict__ sqv,
    const float* __restrict__ sigma, unsigned short* __restrict__ Aout)
{
    int b = blockIdx.z;
    const unsigned short* H = h0b + (long)b * Nn * Ff;
    const float* SQ = sqv + (long)b * Nn;
    unsigned short* Ab = Aout + (long)b * Nn * Nn;

    constexpr int TSZ = 128 * 32;
    __shared__ unsigned short Is[2 * TSZ];
    __shared__ unsigned short Js[2 * TSZ];

    int tid = threadIdx.x;
    int lane = tid & 63;
    int wave = tid >> 6;
    int quad = lane >> 4, l16 = lane & 15;
    int wm = (wave >> 1) * 64, wn = (wave & 1) * 64;
    int i0 = blockIdx.x * 128, j0 = blockIdx.y * 128;

    int sr = lane >> 2, sc = lane & 3;

    f32x4 acc[4][4] = {};

    auto issue = [&](int g) {
        int kk = g << 5;
        unsigned short* Id = Is + (g & 1) * TSZ;
        unsigned short* Jd = Js + (g & 1) * TSZ;
        #pragma unroll
        for (int t = 0; t < 2; ++t) {
            int r = wave * 32 + t * 16 + sr;
            int c = sc ^ SWZ(r);
            async_ld16(H + (long)(i0 + r) * Ff + kk + c * 8,
                       Id + (wave * 32 + t * 16) * 32);
            async_ld16(H + (long)(j0 + r) * Ff + kk + c * 8,
                       Jd + (wave * 32 + t * 16) * 32);
        }
    };

    issue(0);
    for (int g = 0; g < (Ff >> 5); ++g) {
        __syncthreads();
        if (g + 1 < (Ff >> 5)) issue(g + 1);
        const unsigned short* Ib = Is + (g & 1) * TSZ;
        const unsigned short* Jb = Js + (g & 1) * TSZ;
        bf16x8 af[4], bfr[4];
        #pragma unroll
        for (int i = 0; i < 4; ++i) {
            int r = wm + i * 16 + l16;
            af[i] = *(const bf16x8*)&Ib[r * 32 + (quad ^ SWZ(r)) * 8];
        }
        #pragma unroll
        for (int j = 0; j < 4; ++j) {
            int r = wn + j * 16 + l16;
            bfr[j] = *(const bf16x8*)&Jb[r * 32 + (quad ^ SWZ(r)) * 8];
        }
        #pragma unroll
        for (int i = 0; i < 4; ++i)
            #pragma unroll
            for (int j = 0; j < 4; ++j)
                acc[i][j] = __builtin_amdgcn_mfma_f32_16x16x32_bf16(
                    af[i], bfr[j], acc[i][j], 0, 0, 0);
    }

    float s = sigma[0];
    float inv2s2 = 1.0f / (2.0f * s * s);
    #pragma unroll
    for (int i = 0; i < 4; ++i) {
        int rb = i0 + wm + i * 16 + quad * 4;
        #pragma unroll
        for (int j = 0; j < 4; ++j) {
            int c = j0 + wn + j * 16 + l16;
            float sqc = SQ[c];
            f32x4 v = acc[i][j];
            #pragma unroll
            for (int r4 = 0; r4 < 4; ++r4) {
                int r = rb + r4;
                float d = fmaxf(SQ[r] + sqc - 2.0f * v[r4], 0.0f);
                unsigned short a = (r == c) ? (unsigned short)0
                                            : f2bf(__expf(-d * inv2s2));
                Ab[(long)r * Nn + c] = a;
            }
        }
    }
}

// ---------------- weight convert + transpose + gpool zero ----------
__global__ __launch_bounds__(256) void convert_weights(
    const float* __restrict__ Wrel0, const float* __restrict__ Wroot0,
    const float* __restrict__ Wrel1, const float* __restrict__ Wroot1,
    const float* __restrict__ Wrel2, const float* __restrict__ Wroot2,
    const float* __restrict__ Wg,
    unsigned short* __restrict__ T0, unsigned short* __restrict__ T1,
    unsigned short* __restrict__ T2, unsigned short* __restrict__ T3,
    unsigned short* __restrict__ T4, unsigned short* __restrict__ T5,
    unsigned short* __restrict__ TG, float* __restrict__ gpool)
{
    int idx = blockIdx.x * 256 + threadIdx.x;   // total 360448
    if (idx >= 344064) {                         // zero gpool [64*256]
        int e = idx - 344064;
        gpool[e] = 0.f;
        return;
    }
    if (idx >= 327680) {                         // WgT: [128 out][128 in]
        int e = idx - 327680;
        int o = e >> 7, i = e & 127;
        TG[e] = f2bf(Wg[(long)i * 128 + o]);
        return;
    }
    const float* src; unsigned short* dst; int kin; int e;
    if      (idx <  32768) { src = Wrel0;  dst = T0; kin = 128; e = idx; }
    else if (idx <  65536) { src = Wroot0; dst = T1; kin = 128; e = idx - 32768; }
    else if (idx < 131072) { src = Wrel1;  dst = T2; kin = 256; e = idx - 65536; }
    else if (idx < 196608) { src = Wroot1; dst = T3; kin = 256; e = idx - 131072; }
    else if (idx < 262144) { src = Wrel2;  dst = T4; kin = 256; e = idx - 196608; }
    else                   { src = Wroot2; dst = T5; kin = 256; e = idx - 262144; }
    int o = (kin == 128) ? (e >> 7) : (e >> 8);
    int i = e & (kin - 1);
    dst[e] = f2bf(src[(long)i * 256 + o]);      // conv out-dims are all 256
}

// ---------------- head: mean + relu(g@W1+b1) @ Wout + bout ----------------
__global__ __launch_bounds__(256) void head_kernel(
    const float* __restrict__ gpool,
    const float* __restrict__ W1, const float* __restrict__ b1,
    const float* __restrict__ Wout, const float* __restrict__ bout,
    float* __restrict__ out)
{
    int b = blockIdx.x;
    int j = threadIdx.x;
    __shared__ float gs[Hh];
    __shared__ float g2[Hh];
    gs[j] = gpool[b * Hh + j] * (1.0f / (float)Nn);
    __syncthreads();
    float s = b1[j];
    for (int k = 0; k < Hh; ++k) s += gs[k] * W1[k * Hh + j];
    g2[j] = fmaxf(s, 0.f);
    __syncthreads();
    if (j < OUTD) {
        float s2 = bout[j];
        for (int k = 0; k < Hh; ++k) s2 += g2[k] * Wout[k * OUTD + j];
        out[b * OUTD + j] = s2;
    }
}

extern "C" void kernel_launch(void* const* d_in, const int* in_sizes, int n_in,
                              void* d_out, int out_size, void* d_ws, size_t ws_size,
                              hipStream_t stream) {
    const float* x      = (const float*)d_in[0];
    const float* sigma  = (const float*)d_in[4];
    const float* Wg     = (const float*)d_in[5];
    const float* bg     = (const float*)d_in[6];
    const float* Wrel0  = (const float*)d_in[7];
    const float* Wroot0 = (const float*)d_in[8];
    const float* brel0  = (const float*)d_in[9];
    const float* Wrel1  = (const float*)d_in[10];
    const float* Wroot1 = (const float*)d_in[11];
    const float* brel1  = (const float*)d_in[12];
    const float* Wrel2  = (const float*)d_in[13];
    const float* Wroot2 = (const float*)d_in[14];
    const float* brel2  = (const float*)d_in[15];
    const float* W1     = (const float*)d_in[16];
    const float* b1     = (const float*)d_in[17];
    const float* Wout   = (const float*)d_in[18];
    const float* bout   = (const float*)d_in[19];
    float* out = (float*)d_out;

    // Workspace layout (bytes)
    char* ws = (char*)d_ws;
    unsigned short* WgT  = (unsigned short*)(ws + 0);              // 32 KB
    unsigned short* h0b  = (unsigned short*)(ws + 16777216);       // 8 MB
    unsigned short* h0T  = (unsigned short*)(ws + 25165824);       // 8 MB
    float*          sq   = (float*)(ws + 33554432);                // 128 KB
    unsigned short* Aadj = (unsigned short*)(ws + 33685504);       // 32 MB
    unsigned short* agg  = (unsigned short*)(ws + 67239936);       // 16 MB
    unsigned short* h1b  = (unsigned short*)(ws + 84017152);       // 16 MB
    unsigned short* h1T  = (unsigned short*)(ws + 100794368);      // 16 MB
    unsigned short* h2b  = (unsigned short*)(ws + 117571584);      // 16 MB
    unsigned short* h2T  = (unsigned short*)(ws + 134348800);      // 16 MB
    unsigned short* WrelT0  = (unsigned short*)(ws + 167903232);
    unsigned short* WrootT0 = (unsigned short*)(ws + 167968768);
    unsigned short* WrelT1  = (unsigned short*)(ws + 168034304);
    unsigned short* WrootT1 = (unsigned short*)(ws + 168165376);
    unsigned short* WrelT2  = (unsigned short*)(ws + 168296448);
    unsigned short* WrootT2 = (unsigned short*)(ws + 168427520);
    float*          gpool = (float*)(ws + 168558592);              // 64 KB

    // weights -> bf16 transposed + gpool zero
    convert_weights<<<1408, 256, 0, stream>>>(Wrel0, Wroot0, Wrel1, Wroot1, Wrel2, Wroot2, Wg,
                                              WrelT0, WrootT0, WrelT1, WrootT1, WrelT2, WrootT2,
                                              WgT, gpool);

    // h0 (bf16 MFMA), writes node-major + transposed + row sumsq
    h0_mfma<<<dim3(MTOT / 128, 1, 1), 256, 0, stream>>>(x, WgT, bg, h0b, h0T, sq);

    // A = exp(-dist/(2 sigma^2)), zero diag (MFMA Gram, dbuf)
    gram_A_mfma<<<dim3(Nn / 128, Nn / 128, Bsz), 256, 0, stream>>>(h0b, sq, sigma, Aadj);

    // ---- layer 0 ----
    gemm_bf16<64><<<dim3(Nn / 64, 1, Bsz), 256, 0, stream>>>(
        Aadj, h0T, nullptr, nullptr, nullptr, agg, nullptr, nullptr,
        Nn, Ff, Nn, 0,
        (long)Nn * Nn, (long)Ff * Nn, (long)Nn * Ff, 0);
    gemm_bf16<64><<<dim3(MTOT / 64, Hh / 128, 1), 256, 0, stream>>>(
        agg, WrelT0, h0b, WrootT0, brel0, h1b, h1T, nullptr,
        MTOT, Hh, Ff, Ff, 0, 0, 0, 1);

    // ---- layer 1 ----
    gemm_bf16<64><<<dim3(Nn / 64, Hh / 128, Bsz), 256, 0, stream>>>(
        Aadj, h1T, nullptr, nullptr, nullptr, agg, nullptr, nullptr,
        Nn, Hh, Nn, 0,
        (long)Nn * Nn, (long)Hh * Nn, (long)Nn * Hh, 0);
    gemm_bf16<64><<<dim3(MTOT / 64, Hh / 128, 1), 256, 0, stream>>>(
        agg, WrelT1, h1b, WrootT1, brel1, h2b, h2T, nullptr,
        MTOT, Hh, Hh, Hh, 0, 0, 0, 1);

    // ---- layer 2 (no relu; fused mean-pool, no h3 store) ----
    gemm_bf16<64><<<dim3(Nn / 64, Hh / 128, Bsz), 256, 0, stream>>>(
        Aadj, h2T, nullptr, nullptr, nullptr, agg, nullptr, nullptr,
        Nn, Hh, Nn, 0,
        (long)Nn * Nn, (long)Hh * Nn, (long)Nn * Hh, 0);
    gemm_bf16<64><<<dim3(MTOT / 64, Hh / 128, 1), 256, 0, stream>>>(
        agg, WrelT2, h2b, WrootT2, brel2, nullptr, nullptr, gpool,
        MTOT, Hh, Hh, Hh, 0, 0, 0, 4);

    // head (mean + 2-layer MLP)
    head_kernel<<<Bsz, 256, 0, stream>>>(gpool, W1, b1, Wout, bout, out);
}

// Round 7
// 253.946 us; speedup vs baseline: 1.1291x; 1.1291x over previous
//
#include <hip/hip_runtime.h>
#include <math.h>

// Problem constants
#define Bsz 64
#define Nn 512
#define Ff 128
#define Hh 256
#define OUTD 6
#define MTOT (Bsz * Nn)   // 32768

typedef __bf16 bf16x8 __attribute__((ext_vector_type(8)));
typedef float f32x4 __attribute__((ext_vector_type(4)));
typedef int int4v __attribute__((ext_vector_type(4)));
typedef unsigned short ushort4v __attribute__((ext_vector_type(4)));

__device__ __forceinline__ unsigned short f2bf(float f) {
    unsigned u = __float_as_uint(f);
    u += 0x7FFFu + ((u >> 16) & 1u);        // RNE
    return (unsigned short)(u >> 16);
}
__device__ __forceinline__ float bf2f(unsigned short s) {
    return __uint_as_float(((unsigned)s) << 16);
}

// XOR swizzle of the 16B k-chunk within a 64B LDS row (kills ds_read_b128 bank conflicts)
#define SWZ(r) (((r) ^ ((r) >> 2)) & 3)

// async 16B global->LDS (DMA; LDS dest = wave-uniform base + lane*16)
__device__ __forceinline__ void async_ld16(const unsigned short* g, unsigned short* l) {
    __builtin_amdgcn_global_load_lds(
        (const __attribute__((address_space(1))) void*)g,
        (__attribute__((address_space(3))) void*)l,
        16, 0, 0);
}

#define LDH 40           // padded LDS row stride (bf16) for the non-async h0 kernel
#define TSZ (128 * 32)   // one LDS tile: 128 rows x 32 bf16 (8 KB)

// ---------------- bf16 MFMA GEMM, 128x128 tile, double-buffered, fused 2nd pair ----
// out = act( A0@B0 [+ A1@B1] + bias ); B operands TRANSPOSED (BT[n][k]); row stride == K.
// Batched via blockIdx.z strides. flags&1 = relu. CT (optional) = transposed copy
// [graph][n][node] (node = row & 511).
__global__ __launch_bounds__(256) void gemm_bf16(
    const unsigned short* __restrict__ A0, const unsigned short* __restrict__ B0T,
    const unsigned short* __restrict__ A1, const unsigned short* __restrict__ B1T,
    const float* __restrict__ bias,
    unsigned short* __restrict__ C, unsigned short* __restrict__ CT,
    int M, int Ntot, int K0, int K1,
    long strideA0, long strideB0, long strideC, int flags)
{
    int bz = blockIdx.z;
    A0 += (long)bz * strideA0;
    B0T += (long)bz * strideB0;
    C += (long)bz * strideC;

    __shared__ unsigned short As[2 * TSZ];   // double-buffered, 64B rows, swizzled chunks
    __shared__ unsigned short Bs[2 * TSZ];

    int tid = threadIdx.x;
    int lane = tid & 63;
    int wave = tid >> 6;
    int quad = lane >> 4, l16 = lane & 15;
    int wm = (wave >> 1) * 64, wn = (wave & 1) * 64;
    int m0 = blockIdx.x * 128, n0 = blockIdx.y * 128;

    int sr = lane >> 2;        // staging row within 16-row group
    int sc = lane & 3;         // staging chunk slot

    int T0 = K0 >> 5, T1 = K1 >> 5;
    int T = T0 + T1;

    f32x4 acc[4][4] = {};

    // issue tile g's staging loads into buffer (g&1)
    auto issue = [&](int g) {
        const unsigned short* Ag; const unsigned short* Bg; int Kg, kk;
        if (g < T0) { Ag = A0; Bg = B0T; Kg = K0; kk = g << 5; }
        else        { Ag = A1; Bg = B1T; Kg = K1; kk = (g - T0) << 5; }
        unsigned short* Ad = As + (g & 1) * TSZ;
        unsigned short* Bd = Bs + (g & 1) * TSZ;
        #pragma unroll
        for (int t = 0; t < 2; ++t) {
            int r = wave * 32 + t * 16 + sr;
            int c = sc ^ SWZ(r);
            async_ld16(Ag + (long)(m0 + r) * Kg + kk + c * 8,
                       Ad + (wave * 32 + t * 16) * 32);
            async_ld16(Bg + (long)(n0 + r) * Kg + kk + c * 8,
                       Bd + (wave * 32 + t * 16) * 32);
        }
    };

    issue(0);
    for (int g = 0; g < T; ++g) {
        __syncthreads();                      // drains tile g's loads (issued last iter)
        if (g + 1 < T) issue(g + 1);          // overlaps with compute of tile g
        const unsigned short* Ab = As + (g & 1) * TSZ;
        const unsigned short* Bb = Bs + (g & 1) * TSZ;
        bf16x8 af[4], bfr[4];
        #pragma unroll
        for (int i = 0; i < 4; ++i) {
            int r = wm + i * 16 + l16;
            af[i] = *(const bf16x8*)&Ab[r * 32 + (quad ^ SWZ(r)) * 8];
        }
        #pragma unroll
        for (int j = 0; j < 4; ++j) {
            int r = wn + j * 16 + l16;
            bfr[j] = *(const bf16x8*)&Bb[r * 32 + (quad ^ SWZ(r)) * 8];
        }
        #pragma unroll
        for (int i = 0; i < 4; ++i)
            #pragma unroll
            for (int j = 0; j < 4; ++j)
                acc[i][j] = __builtin_amdgcn_mfma_f32_16x16x32_bf16(
                    af[i], bfr[j], acc[i][j], 0, 0, 0);
    }

    // ---- epilogue. C/D layout: col = lane&15, row = quad*4 + reg ----
    int ldc = Ntot;
    #pragma unroll
    for (int i = 0; i < 4; ++i) {
        int mb = m0 + wm + i * 16 + quad * 4;
        #pragma unroll
        for (int j = 0; j < 4; ++j) {
            int n = n0 + wn + j * 16 + l16;
            f32x4 v = acc[i][j];
            float bv = bias ? bias[n] : 0.0f;
            float o0 = v[0] + bv, o1 = v[1] + bv, o2 = v[2] + bv, o3 = v[3] + bv;
            if (flags & 1) {
                o0 = fmaxf(o0, 0.f); o1 = fmaxf(o1, 0.f);
                o2 = fmaxf(o2, 0.f); o3 = fmaxf(o3, 0.f);
            }
            unsigned short s0 = f2bf(o0), s1 = f2bf(o1), s2 = f2bf(o2), s3 = f2bf(o3);
            C[(long)(mb + 0) * ldc + n] = s0;
            C[(long)(mb + 1) * ldc + n] = s1;
            C[(long)(mb + 2) * ldc + n] = s2;
            C[(long)(mb + 3) * ldc + n] = s3;
            if (CT) {
                ushort4v p; p[0] = s0; p[1] = s1; p[2] = s2; p[3] = s3;
                long ti = ((long)(mb >> 9) * Ntot + n) * 512 + (mb & 511);
                *(ushort4v*)&CT[ti] = p;
            }
        }
    }
}

// ---------------- h0 = bf16(x) @ WgT + bg  (MFMA; writes h0b + h0T + sq) ------------
__global__ __launch_bounds__(256) void h0_mfma(
    const float* __restrict__ x, const unsigned short* __restrict__ WgT,
    const float* __restrict__ bg,
    unsigned short* __restrict__ h0b, unsigned short* __restrict__ h0T,
    float* __restrict__ sqv)
{
    __shared__ unsigned short As[128 * LDH];
    __shared__ unsigned short Bs[128 * LDH];
    __shared__ float rsq[128];

    int tid = threadIdx.x;
    int lane = tid & 63;
    int wave = tid >> 6;
    int quad = lane >> 4, l16 = lane & 15;
    int wm = (wave >> 1) * 64, wn = (wave & 1) * 64;
    int m0 = blockIdx.x * 128;          // N = 128 (single column block)

    f32x4 acc[4][4] = {};

    for (int k0 = 0; k0 < Ff; k0 += 32) {
        __syncthreads();
        #pragma unroll
        for (int l = 0; l < 2; ++l) {
            int idx = tid + l * 256;
            int r = idx >> 2, ch = idx & 3;
            const float* px = x + (long)(m0 + r) * Ff + k0 + ch * 8;
            float4 xa = *(const float4*)px;
            float4 xb = *(const float4*)(px + 4);
            ushort4v pa, pb;
            pa[0] = f2bf(xa.x); pa[1] = f2bf(xa.y); pa[2] = f2bf(xa.z); pa[3] = f2bf(xa.w);
            pb[0] = f2bf(xb.x); pb[1] = f2bf(xb.y); pb[2] = f2bf(xb.z); pb[3] = f2bf(xb.w);
            *(ushort4v*)&As[r * LDH + ch * 8] = pa;
            *(ushort4v*)&As[r * LDH + ch * 8 + 4] = pb;
            int4v vb = *(const int4v*)(WgT + (long)r * Ff + k0 + ch * 8);
            *(int4v*)&Bs[r * LDH + ch * 8] = vb;
        }
        __syncthreads();
        bf16x8 af[4], bfr[4];
        #pragma unroll
        for (int i = 0; i < 4; ++i)
            af[i] = *(const bf16x8*)&As[(wm + i * 16 + l16) * LDH + quad * 8];
        #pragma unroll
        for (int j = 0; j < 4; ++j)
            bfr[j] = *(const bf16x8*)&Bs[(wn + j * 16 + l16) * LDH + quad * 8];
        #pragma unroll
        for (int i = 0; i < 4; ++i)
            #pragma unroll
            for (int j = 0; j < 4; ++j)
                acc[i][j] = __builtin_amdgcn_mfma_f32_16x16x32_bf16(
                    af[i], bfr[j], acc[i][j], 0, 0, 0);
    }

    if (tid < 128) rsq[tid] = 0.f;
    __syncthreads();

    #pragma unroll
    for (int i = 0; i < 4; ++i) {
        int lrow = wm + i * 16 + quad * 4;   // local row of first of 4
        int mb = m0 + lrow;
        float rp0 = 0.f, rp1 = 0.f, rp2 = 0.f, rp3 = 0.f;
        #pragma unroll
        for (int j = 0; j < 4; ++j) {
            int n = wn + j * 16 + l16;
            f32x4 v = acc[i][j];
            float bv = bg[n];
            unsigned short s0 = f2bf(v[0] + bv), s1 = f2bf(v[1] + bv);
            unsigned short s2 = f2bf(v[2] + bv), s3 = f2bf(v[3] + bv);
            h0b[(long)(mb + 0) * Ff + n] = s0;
            h0b[(long)(mb + 1) * Ff + n] = s1;
            h0b[(long)(mb + 2) * Ff + n] = s2;
            h0b[(long)(mb + 3) * Ff + n] = s3;
            ushort4v p; p[0] = s0; p[1] = s1; p[2] = s2; p[3] = s3;
            long ti = ((long)(mb >> 9) * Ff + n) * 512 + (mb & 511);
            *(ushort4v*)&h0T[ti] = p;
            float f0 = bf2f(s0), f1 = bf2f(s1), f2 = bf2f(s2), f3 = bf2f(s3);
            rp0 += f0 * f0; rp1 += f1 * f1; rp2 += f2 * f2; rp3 += f3 * f3;
        }
        // reduce across the 16 lanes (same quad) covering these 4 rows
        #pragma unroll
        for (int m = 1; m < 16; m <<= 1) {
            rp0 += __shfl_xor(rp0, m);
            rp1 += __shfl_xor(rp1, m);
            rp2 += __shfl_xor(rp2, m);
            rp3 += __shfl_xor(rp3, m);
        }
        if (l16 == 0) {   // two waves share rows -> atomic
            atomicAdd(&rsq[lrow + 0], rp0);
            atomicAdd(&rsq[lrow + 1], rp1);
            atomicAdd(&rsq[lrow + 2], rp2);
            atomicAdd(&rsq[lrow + 3], rp3);
        }
    }
    __syncthreads();
    if (tid < 128) sqv[m0 + tid] = rsq[tid];
}

// ---------------- Gram -> Gaussian adjacency A via MFMA (dbuf; also A row-sums w) ---
__global__ __launch_bounds__(256) void gram_A_mfma(
    const unsigned short* __restrict__ h0b, const float* __restrict__ sqv,
    const float* __restrict__ sigma, unsigned short* __restrict__ Aout,
    float* __restrict__ w)
{
    int b = blockIdx.z;
    const unsigned short* H = h0b + (long)b * Nn * Ff;
    const float* SQ = sqv + (long)b * Nn;
    unsigned short* Ab = Aout + (long)b * Nn * Nn;

    __shared__ unsigned short Is[2 * TSZ];
    __shared__ unsigned short Js[2 * TSZ];
    __shared__ float rsum[128];

    int tid = threadIdx.x;
    int lane = tid & 63;
    int wave = tid >> 6;
    int quad = lane >> 4, l16 = lane & 15;
    int wm = (wave >> 1) * 64, wn = (wave & 1) * 64;
    int i0 = blockIdx.x * 128, j0 = blockIdx.y * 128;

    int sr = lane >> 2, sc = lane & 3;

    f32x4 acc[4][4] = {};

    auto issue = [&](int g) {
        int kk = g << 5;
        unsigned short* Id = Is + (g & 1) * TSZ;
        unsigned short* Jd = Js + (g & 1) * TSZ;
        #pragma unroll
        for (int t = 0; t < 2; ++t) {
            int r = wave * 32 + t * 16 + sr;
            int c = sc ^ SWZ(r);
            async_ld16(H + (long)(i0 + r) * Ff + kk + c * 8,
                       Id + (wave * 32 + t * 16) * 32);
            async_ld16(H + (long)(j0 + r) * Ff + kk + c * 8,
                       Jd + (wave * 32 + t * 16) * 32);
        }
    };

    issue(0);
    for (int g = 0; g < (Ff >> 5); ++g) {
        __syncthreads();
        if (g + 1 < (Ff >> 5)) issue(g + 1);
        const unsigned short* Ib = Is + (g & 1) * TSZ;
        const unsigned short* Jb = Js + (g & 1) * TSZ;
        bf16x8 af[4], bfr[4];
        #pragma unroll
        for (int i = 0; i < 4; ++i) {
            int r = wm + i * 16 + l16;
            af[i] = *(const bf16x8*)&Ib[r * 32 + (quad ^ SWZ(r)) * 8];
        }
        #pragma unroll
        for (int j = 0; j < 4; ++j) {
            int r = wn + j * 16 + l16;
            bfr[j] = *(const bf16x8*)&Jb[r * 32 + (quad ^ SWZ(r)) * 8];
        }
        #pragma unroll
        for (int i = 0; i < 4; ++i)
            #pragma unroll
            for (int j = 0; j < 4; ++j)
                acc[i][j] = __builtin_amdgcn_mfma_f32_16x16x32_bf16(
                    af[i], bfr[j], acc[i][j], 0, 0, 0);
    }

    if (tid < 128) rsum[tid] = 0.f;
    __syncthreads();

    float s = sigma[0];
    float inv2s2 = 1.0f / (2.0f * s * s);
    #pragma unroll
    for (int i = 0; i < 4; ++i) {
        int lrow = wm + i * 16 + quad * 4;
        int rb = i0 + lrow;
        float rs0 = 0.f, rs1 = 0.f, rs2 = 0.f, rs3 = 0.f;
        #pragma unroll
        for (int j = 0; j < 4; ++j) {
            int c = j0 + wn + j * 16 + l16;
            float sqc = SQ[c];
            f32x4 v = acc[i][j];
            float av[4];
            #pragma unroll
            for (int r4 = 0; r4 < 4; ++r4) {
                int r = rb + r4;
                float d = fmaxf(SQ[r] + sqc - 2.0f * v[r4], 0.0f);
                unsigned short a = (r == c) ? (unsigned short)0
                                            : f2bf(__expf(-d * inv2s2));
                Ab[(long)r * Nn + c] = a;
                av[r4] = bf2f(a);
            }
            rs0 += av[0]; rs1 += av[1]; rs2 += av[2]; rs3 += av[3];
        }
        #pragma unroll
        for (int m = 1; m < 16; m <<= 1) {
            rs0 += __shfl_xor(rs0, m);
            rs1 += __shfl_xor(rs1, m);
            rs2 += __shfl_xor(rs2, m);
            rs3 += __shfl_xor(rs3, m);
        }
        if (l16 == 0) {
            atomicAdd(&rsum[lrow + 0], rs0);
            atomicAdd(&rsum[lrow + 1], rs1);
            atomicAdd(&rsum[lrow + 2], rs2);
            atomicAdd(&rsum[lrow + 3], rs3);
        }
    }
    __syncthreads();
    if (tid < 128) atomicAdd(&w[(long)b * Nn + i0 + tid], rsum[tid]);
}

// ---------------- weight convert + transpose + zero w/v/m ----------
__global__ __launch_bounds__(256) void convert_weights(
    const float* __restrict__ Wrel0, const float* __restrict__ Wroot0,
    const float* __restrict__ Wrel1, const float* __restrict__ Wroot1,
    const float* __restrict__ Wg,
    unsigned short* __restrict__ T0, unsigned short* __restrict__ T1,
    unsigned short* __restrict__ T2, unsigned short* __restrict__ T3,
    unsigned short* __restrict__ TG,
    float* __restrict__ w, float* __restrict__ vm)
{
    int idx = blockIdx.x * 256 + threadIdx.x;   // total 278528
    if (idx >= 245760) { vm[idx - 245760] = 0.f; return; }   // v+m: 32768 floats
    if (idx >= 212992) { w[idx - 212992] = 0.f; return; }    // w: 32768 floats
    if (idx >= 196608) {                         // WgT: [128 out][128 in]
        int e = idx - 196608;
        int o = e >> 7, i = e & 127;
        TG[e] = f2bf(Wg[(long)i * 128 + o]);
        return;
    }
    const float* src; unsigned short* dst; int kin; int e;
    if      (idx <  32768) { src = Wrel0;  dst = T0; kin = 128; e = idx; }
    else if (idx <  65536) { src = Wroot0; dst = T1; kin = 128; e = idx - 32768; }
    else if (idx < 131072) { src = Wrel1;  dst = T2; kin = 256; e = idx - 65536; }
    else                   { src = Wroot1; dst = T3; kin = 256; e = idx - 131072; }
    int o = (kin == 128) ? (e >> 7) : (e >> 8);
    int i = e & (kin - 1);
    dst[e] = f2bf(src[(long)i * 256 + o]);      // conv out-dims are all 256
}

// ---------------- v[b][c] = sum_j w[b][j]*h2[b][j][c]; m[b][c] = sum_j h2[b][j][c] --
__global__ __launch_bounds__(256) void reduce_h2(
    const unsigned short* __restrict__ h2b, const float* __restrict__ w,
    float* __restrict__ v, float* __restrict__ m)
{
    int b = blockIdx.x;
    int jc = blockIdx.y;        // 0..3, 128 nodes each
    int c = threadIdx.x;        // 0..255
    const unsigned short* H = h2b + ((long)b * Nn + jc * 128) * Hh + c;
    const float* wp = w + (long)b * Nn + jc * 128;
    float vp = 0.f, mp = 0.f;
    #pragma unroll 4
    for (int j = 0; j < 128; ++j) {
        float val = bf2f(H[(long)j * Hh]);
        mp += val;
        vp += wp[j] * val;
    }
    atomicAdd(&v[b * Hh + c], vp);
    atomicAdd(&m[b * Hh + c], mp);
}

// ---------------- head: layer2-collapse + mean + MLP ----------------
// g = (v/N)@Wrel2 + (m/N)@Wroot2 + brel2;  out = relu(g@W1+b1)@Wout + bout
__global__ __launch_bounds__(256) void head_kernel(
    const float* __restrict__ v, const float* __restrict__ m,
    const float* __restrict__ Wrel2, const float* __restrict__ Wroot2,
    const float* __restrict__ brel2,
    const float* __restrict__ W1, const float* __restrict__ b1,
    const float* __restrict__ Wout, const float* __restrict__ bout,
    float* __restrict__ out)
{
    int b = blockIdx.x;
    int j = threadIdx.x;
    __shared__ float vs[Hh], ms[Hh], gs[Hh], g2[Hh];
    vs[j] = v[b * Hh + j] * (1.0f / (float)Nn);
    ms[j] = m[b * Hh + j] * (1.0f / (float)Nn);
    __syncthreads();
    float s = brel2[j];
    for (int c = 0; c < Hh; ++c)
        s += vs[c] * Wrel2[c * Hh + j] + ms[c] * Wroot2[c * Hh + j];
    gs[j] = s;
    __syncthreads();
    float t = b1[j];
    for (int k = 0; k < Hh; ++k) t += gs[k] * W1[k * Hh + j];
    g2[j] = fmaxf(t, 0.f);
    __syncthreads();
    if (j < OUTD) {
        float s2 = bout[j];
        for (int k = 0; k < Hh; ++k) s2 += g2[k] * Wout[k * OUTD + j];
        out[b * OUTD + j] = s2;
    }
}

extern "C" void kernel_launch(void* const* d_in, const int* in_sizes, int n_in,
                              void* d_out, int out_size, void* d_ws, size_t ws_size,
                              hipStream_t stream) {
    const float* x      = (const float*)d_in[0];
    const float* sigma  = (const float*)d_in[4];
    const float* Wg     = (const float*)d_in[5];
    const float* bg     = (const float*)d_in[6];
    const float* Wrel0  = (const float*)d_in[7];
    const float* Wroot0 = (const float*)d_in[8];
    const float* brel0  = (const float*)d_in[9];
    const float* Wrel1  = (const float*)d_in[10];
    const float* Wroot1 = (const float*)d_in[11];
    const float* brel1  = (const float*)d_in[12];
    const float* Wrel2  = (const float*)d_in[13];
    const float* Wroot2 = (const float*)d_in[14];
    const float* brel2  = (const float*)d_in[15];
    const float* W1     = (const float*)d_in[16];
    const float* b1     = (const float*)d_in[17];
    const float* Wout   = (const float*)d_in[18];
    const float* bout   = (const float*)d_in[19];
    float* out = (float*)d_out;

    // Workspace layout (bytes)
    char* ws = (char*)d_ws;
    unsigned short* WgT  = (unsigned short*)(ws + 0);              // 32 KB
    unsigned short* h0b  = (unsigned short*)(ws + 16777216);       // 8 MB
    unsigned short* h0T  = (unsigned short*)(ws + 25165824);       // 8 MB
    float*          sq   = (float*)(ws + 33554432);                // 128 KB
    unsigned short* Aadj = (unsigned short*)(ws + 33685504);       // 32 MB
    unsigned short* agg  = (unsigned short*)(ws + 67239936);       // 16 MB
    unsigned short* h1b  = (unsigned short*)(ws + 84017152);       // 16 MB
    unsigned short* h1T  = (unsigned short*)(ws + 100794368);      // 16 MB
    unsigned short* h2b  = (unsigned short*)(ws + 117571584);      // 16 MB
    unsigned short* WrelT0  = (unsigned short*)(ws + 167903232);   // 64 KB
    unsigned short* WrootT0 = (unsigned short*)(ws + 167968768);   // 64 KB
    unsigned short* WrelT1  = (unsigned short*)(ws + 168034304);   // 128 KB
    unsigned short* WrootT1 = (unsigned short*)(ws + 168165376);   // 128 KB
    float*          w    = (float*)(ws + 168558592);               // 128 KB (A row sums)
    float*          v    = (float*)(ws + 168689664);               // 64 KB
    float*          m    = (float*)(ws + 168755200);               // 64 KB

    // weights -> bf16 transposed + zero w/v/m
    convert_weights<<<1088, 256, 0, stream>>>(Wrel0, Wroot0, Wrel1, Wroot1, Wg,
                                              WrelT0, WrootT0, WrelT1, WrootT1, WgT,
                                              w, v /* vm base: v then m contiguous */);

    // h0 (bf16 MFMA), writes node-major + transposed + row sumsq
    h0_mfma<<<dim3(MTOT / 128, 1, 1), 256, 0, stream>>>(x, WgT, bg, h0b, h0T, sq);

    // A = exp(-dist/(2 sigma^2)), zero diag; accumulate row sums w
    gram_A_mfma<<<dim3(Nn / 128, Nn / 128, Bsz), 256, 0, stream>>>(h0b, sq, sigma, Aadj, w);

    // ---- layer 0 ----
    gemm_bf16<<<dim3(4, 1, Bsz), 256, 0, stream>>>(
        Aadj, h0T, nullptr, nullptr, nullptr, agg, nullptr,
        Nn, Ff, Nn, 0,
        (long)Nn * Nn, (long)Ff * Nn, (long)Nn * Ff, 0);
    gemm_bf16<<<dim3(MTOT / 128, Hh / 128, 1), 256, 0, stream>>>(
        agg, WrelT0, h0b, WrootT0, brel0, h1b, h1T,
        MTOT, Hh, Ff, Ff, 0, 0, 0, 1);

    // ---- layer 1 ----
    gemm_bf16<<<dim3(4, 2, Bsz), 256, 0, stream>>>(
        Aadj, h1T, nullptr, nullptr, nullptr, agg, nullptr,
        Nn, Hh, Nn, 0,
        (long)Nn * Nn, (long)Hh * Nn, (long)Nn * Hh, 0);
    gemm_bf16<<<dim3(MTOT / 128, Hh / 128, 1), 256, 0, stream>>>(
        agg, WrelT1, h1b, WrootT1, brel1, h2b, nullptr,
        MTOT, Hh, Hh, Hh, 0, 0, 0, 1);

    // ---- layer 2 collapsed: v = w@h2, m = colsum(h2) ----
    reduce_h2<<<dim3(Bsz, 4), 256, 0, stream>>>(h2b, w, v, m);

    // head (layer-2 projection + mean + 2-layer MLP, fp32)
    head_kernel<<<Bsz, 256, 0, stream>>>(v, m, Wrel2, Wroot2, brel2,
                                         W1, b1, Wout, bout, out);
}

// Round 8
// 231.722 us; speedup vs baseline: 1.2374x; 1.0959x over previous
//
#include <hip/hip_runtime.h>
#include <math.h>

// Problem constants
#define Bsz 64
#define Nn 512
#define Ff 128
#define Hh 256
#define OUTD 6
#define MTOT (Bsz * Nn)   // 32768

typedef __bf16 bf16x8 __attribute__((ext_vector_type(8)));
typedef float f32x4 __attribute__((ext_vector_type(4)));
typedef int int4v __attribute__((ext_vector_type(4)));
typedef unsigned short ushort4v __attribute__((ext_vector_type(4)));

__device__ __forceinline__ unsigned short f2bf(float f) {
    unsigned u = __float_as_uint(f);
    u += 0x7FFFu + ((u >> 16) & 1u);        // RNE
    return (unsigned short)(u >> 16);
}
__device__ __forceinline__ float bf2f(unsigned short s) {
    return __uint_as_float(((unsigned)s) << 16);
}

// XOR swizzle of the 16B k-chunk within a 64B LDS row (kills ds_read_b128 bank conflicts)
#define SWZ(r) (((r) ^ ((r) >> 2)) & 3)

// async 16B global->LDS (DMA; LDS dest = wave-uniform base + lane*16)
__device__ __forceinline__ void async_ld16(const unsigned short* g, unsigned short* l) {
    __builtin_amdgcn_global_load_lds(
        (const __attribute__((address_space(1))) void*)g,
        (__attribute__((address_space(3))) void*)l,
        16, 0, 0);
}

#define LDH 40           // padded LDS row stride (bf16) for the non-async h0 kernel
#define TSZ (128 * 32)   // one LDS tile: 128 rows x 32 bf16 (8 KB)

// ---------------- bf16 MFMA GEMM, 128x128 tile, 8 waves, dbuf, fused 2nd pair ------
// out = act( A0@B0 [+ A1@B1] + bias ); B operands TRANSPOSED (BT[n][k]); row stride == K.
// flags&1 = relu; flags&8 = decode 1D grid (id: graph = id&63, tile = id>>6, x=t&3,
// y=t>>2 — keeps a graph's tiles on one XCD). CT = transposed copy [graph][n][node].
__global__ __launch_bounds__(512) void gemm_bf16(
    const unsigned short* __restrict__ A0, const unsigned short* __restrict__ B0T,
    const unsigned short* __restrict__ A1, const unsigned short* __restrict__ B1T,
    const float* __restrict__ bias,
    unsigned short* __restrict__ C, unsigned short* __restrict__ CT,
    int M, int Ntot, int K0, int K1,
    long strideA0, long strideB0, long strideC, int flags)
{
    int bx, by, bz;
    if (flags & 8) {
        int id = blockIdx.x;
        bz = id & 63;
        int t = id >> 6;
        bx = t & 3;
        by = t >> 2;
    } else { bx = blockIdx.x; by = blockIdx.y; bz = blockIdx.z; }

    A0 += (long)bz * strideA0;
    B0T += (long)bz * strideB0;
    C += (long)bz * strideC;

    __shared__ unsigned short As[2 * TSZ];   // double-buffered, 64B rows, swizzled chunks
    __shared__ unsigned short Bs[2 * TSZ];

    int tid = threadIdx.x;
    int lane = tid & 63;
    int wave = tid >> 6;                 // 0..7
    int quad = lane >> 4, l16 = lane & 15;
    int wm = (wave >> 1) * 32, wn = (wave & 1) * 64;   // 32x64 per wave
    int m0 = bx * 128, n0 = by * 128;

    int sr = lane >> 2;        // staging row within 16-row group
    int sc = lane & 3;         // staging chunk slot

    int T0 = K0 >> 5, T1 = K1 >> 5;
    int T = T0 + T1;

    f32x4 acc[2][4] = {};

    // issue tile g's staging loads into buffer (g&1); each wave stages 16 rows of A + B
    auto issue = [&](int g) {
        const unsigned short* Ag; const unsigned short* Bg; int Kg, kk;
        if (g < T0) { Ag = A0; Bg = B0T; Kg = K0; kk = g << 5; }
        else        { Ag = A1; Bg = B1T; Kg = K1; kk = (g - T0) << 5; }
        unsigned short* Ad = As + (g & 1) * TSZ;
        unsigned short* Bd = Bs + (g & 1) * TSZ;
        int r = wave * 16 + sr;
        int c = sc ^ SWZ(r);
        async_ld16(Ag + (long)(m0 + r) * Kg + kk + c * 8, Ad + (wave * 16) * 32);
        async_ld16(Bg + (long)(n0 + r) * Kg + kk + c * 8, Bd + (wave * 16) * 32);
    };

    issue(0);
    for (int g = 0; g < T; ++g) {
        __syncthreads();                      // drains tile g's loads (issued last iter)
        if (g + 1 < T) issue(g + 1);          // overlaps with compute of tile g
        const unsigned short* Ab = As + (g & 1) * TSZ;
        const unsigned short* Bb = Bs + (g & 1) * TSZ;
        bf16x8 af[2], bfr[4];
        #pragma unroll
        for (int i = 0; i < 2; ++i) {
            int r = wm + i * 16 + l16;
            af[i] = *(const bf16x8*)&Ab[r * 32 + (quad ^ SWZ(r)) * 8];
        }
        #pragma unroll
        for (int j = 0; j < 4; ++j) {
            int r = wn + j * 16 + l16;
            bfr[j] = *(const bf16x8*)&Bb[r * 32 + (quad ^ SWZ(r)) * 8];
        }
        #pragma unroll
        for (int i = 0; i < 2; ++i)
            #pragma unroll
            for (int j = 0; j < 4; ++j)
                acc[i][j] = __builtin_amdgcn_mfma_f32_16x16x32_bf16(
                    af[i], bfr[j], acc[i][j], 0, 0, 0);
    }

    // ---- epilogue. C/D layout: col = lane&15, row = quad*4 + reg ----
    int ldc = Ntot;
    #pragma unroll
    for (int i = 0; i < 2; ++i) {
        int mb = m0 + wm + i * 16 + quad * 4;
        #pragma unroll
        for (int j = 0; j < 4; ++j) {
            int n = n0 + wn + j * 16 + l16;
            f32x4 v = acc[i][j];
            float bv = bias ? bias[n] : 0.0f;
            float o0 = v[0] + bv, o1 = v[1] + bv, o2 = v[2] + bv, o3 = v[3] + bv;
            if (flags & 1) {
                o0 = fmaxf(o0, 0.f); o1 = fmaxf(o1, 0.f);
                o2 = fmaxf(o2, 0.f); o3 = fmaxf(o3, 0.f);
            }
            unsigned short s0 = f2bf(o0), s1 = f2bf(o1), s2 = f2bf(o2), s3 = f2bf(o3);
            C[(long)(mb + 0) * ldc + n] = s0;
            C[(long)(mb + 1) * ldc + n] = s1;
            C[(long)(mb + 2) * ldc + n] = s2;
            C[(long)(mb + 3) * ldc + n] = s3;
            if (CT) {
                ushort4v p; p[0] = s0; p[1] = s1; p[2] = s2; p[3] = s3;
                long ti = ((long)(mb >> 9) * Ntot + n) * 512 + (mb & 511);
                *(ushort4v*)&CT[ti] = p;
            }
        }
    }
}

// ---------------- h0 = bf16(x) @ WgT + bg  (MFMA; writes h0b + h0T + sq) ------------
__global__ __launch_bounds__(256) void h0_mfma(
    const float* __restrict__ x, const unsigned short* __restrict__ WgT,
    const float* __restrict__ bg,
    unsigned short* __restrict__ h0b, unsigned short* __restrict__ h0T,
    float* __restrict__ sqv)
{
    __shared__ unsigned short As[128 * LDH];
    __shared__ unsigned short Bs[128 * LDH];
    __shared__ float rsq[128];

    int tid = threadIdx.x;
    int lane = tid & 63;
    int wave = tid >> 6;
    int quad = lane >> 4, l16 = lane & 15;
    int wm = (wave >> 1) * 64, wn = (wave & 1) * 64;
    int m0 = blockIdx.x * 128;          // N = 128 (single column block)

    f32x4 acc[4][4] = {};

    for (int k0 = 0; k0 < Ff; k0 += 32) {
        __syncthreads();
        #pragma unroll
        for (int l = 0; l < 2; ++l) {
            int idx = tid + l * 256;
            int r = idx >> 2, ch = idx & 3;
            const float* px = x + (long)(m0 + r) * Ff + k0 + ch * 8;
            float4 xa = *(const float4*)px;
            float4 xb = *(const float4*)(px + 4);
            ushort4v pa, pb;
            pa[0] = f2bf(xa.x); pa[1] = f2bf(xa.y); pa[2] = f2bf(xa.z); pa[3] = f2bf(xa.w);
            pb[0] = f2bf(xb.x); pb[1] = f2bf(xb.y); pb[2] = f2bf(xb.z); pb[3] = f2bf(xb.w);
            *(ushort4v*)&As[r * LDH + ch * 8] = pa;
            *(ushort4v*)&As[r * LDH + ch * 8 + 4] = pb;
            int4v vb = *(const int4v*)(WgT + (long)r * Ff + k0 + ch * 8);
            *(int4v*)&Bs[r * LDH + ch * 8] = vb;
        }
        __syncthreads();
        bf16x8 af[4], bfr[4];
        #pragma unroll
        for (int i = 0; i < 4; ++i)
            af[i] = *(const bf16x8*)&As[(wm + i * 16 + l16) * LDH + quad * 8];
        #pragma unroll
        for (int j = 0; j < 4; ++j)
            bfr[j] = *(const bf16x8*)&Bs[(wn + j * 16 + l16) * LDH + quad * 8];
        #pragma unroll
        for (int i = 0; i < 4; ++i)
            #pragma unroll
            for (int j = 0; j < 4; ++j)
                acc[i][j] = __builtin_amdgcn_mfma_f32_16x16x32_bf16(
                    af[i], bfr[j], acc[i][j], 0, 0, 0);
    }

    if (tid < 128) rsq[tid] = 0.f;
    __syncthreads();

    #pragma unroll
    for (int i = 0; i < 4; ++i) {
        int lrow = wm + i * 16 + quad * 4;   // local row of first of 4
        int mb = m0 + lrow;
        float rp0 = 0.f, rp1 = 0.f, rp2 = 0.f, rp3 = 0.f;
        #pragma unroll
        for (int j = 0; j < 4; ++j) {
            int n = wn + j * 16 + l16;
            f32x4 v = acc[i][j];
            float bv = bg[n];
            unsigned short s0 = f2bf(v[0] + bv), s1 = f2bf(v[1] + bv);
            unsigned short s2 = f2bf(v[2] + bv), s3 = f2bf(v[3] + bv);
            h0b[(long)(mb + 0) * Ff + n] = s0;
            h0b[(long)(mb + 1) * Ff + n] = s1;
            h0b[(long)(mb + 2) * Ff + n] = s2;
            h0b[(long)(mb + 3) * Ff + n] = s3;
            ushort4v p; p[0] = s0; p[1] = s1; p[2] = s2; p[3] = s3;
            long ti = ((long)(mb >> 9) * Ff + n) * 512 + (mb & 511);
            *(ushort4v*)&h0T[ti] = p;
            float f0 = bf2f(s0), f1 = bf2f(s1), f2 = bf2f(s2), f3 = bf2f(s3);
            rp0 += f0 * f0; rp1 += f1 * f1; rp2 += f2 * f2; rp3 += f3 * f3;
        }
        // reduce across the 16 lanes (same quad) covering these 4 rows
        #pragma unroll
        for (int m = 1; m < 16; m <<= 1) {
            rp0 += __shfl_xor(rp0, m);
            rp1 += __shfl_xor(rp1, m);
            rp2 += __shfl_xor(rp2, m);
            rp3 += __shfl_xor(rp3, m);
        }
        if (l16 == 0) {   // two waves share rows -> atomic
            atomicAdd(&rsq[lrow + 0], rp0);
            atomicAdd(&rsq[lrow + 1], rp1);
            atomicAdd(&rsq[lrow + 2], rp2);
            atomicAdd(&rsq[lrow + 3], rp3);
        }
    }
    __syncthreads();
    if (tid < 128) sqv[m0 + tid] = rsq[tid];
}

// ---------------- Gram -> adjacency A via MFMA (8 waves, dbuf; also row-sums w) -----
// 1D grid: graph = id&63, tile = id>>6 (x = t&3, y = t>>2) — XCD locality.
__global__ __launch_bounds__(512) void gram_A_mfma(
    const unsigned short* __restrict__ h0b, const float* __restrict__ sqv,
    const float* __restrict__ sigma, unsigned short* __restrict__ Aout,
    float* __restrict__ w)
{
    int id = blockIdx.x;
    int b = id & 63;
    int t = id >> 6;
    int i0 = (t & 3) * 128, j0 = (t >> 2) * 128;

    const unsigned short* H = h0b + (long)b * Nn * Ff;
    const float* SQ = sqv + (long)b * Nn;
    unsigned short* Ab = Aout + (long)b * Nn * Nn;

    __shared__ unsigned short Is[2 * TSZ];
    __shared__ unsigned short Js[2 * TSZ];
    __shared__ float rsum[128];

    int tid = threadIdx.x;
    int lane = tid & 63;
    int wave = tid >> 6;                 // 0..7
    int quad = lane >> 4, l16 = lane & 15;
    int wm = (wave >> 1) * 32, wn = (wave & 1) * 64;

    int sr = lane >> 2, sc = lane & 3;

    f32x4 acc[2][4] = {};

    auto issue = [&](int g) {
        int kk = g << 5;
        unsigned short* Id = Is + (g & 1) * TSZ;
        unsigned short* Jd = Js + (g & 1) * TSZ;
        int r = wave * 16 + sr;
        int c = sc ^ SWZ(r);
        async_ld16(H + (long)(i0 + r) * Ff + kk + c * 8, Id + (wave * 16) * 32);
        async_ld16(H + (long)(j0 + r) * Ff + kk + c * 8, Jd + (wave * 16) * 32);
    };

    issue(0);
    for (int g = 0; g < (Ff >> 5); ++g) {
        __syncthreads();
        if (g + 1 < (Ff >> 5)) issue(g + 1);
        const unsigned short* Ib = Is + (g & 1) * TSZ;
        const unsigned short* Jb = Js + (g & 1) * TSZ;
        bf16x8 af[2], bfr[4];
        #pragma unroll
        for (int i = 0; i < 2; ++i) {
            int r = wm + i * 16 + l16;
            af[i] = *(const bf16x8*)&Ib[r * 32 + (quad ^ SWZ(r)) * 8];
        }
        #pragma unroll
        for (int j = 0; j < 4; ++j) {
            int r = wn + j * 16 + l16;
            bfr[j] = *(const bf16x8*)&Jb[r * 32 + (quad ^ SWZ(r)) * 8];
        }
        #pragma unroll
        for (int i = 0; i < 2; ++i)
            #pragma unroll
            for (int j = 0; j < 4; ++j)
                acc[i][j] = __builtin_amdgcn_mfma_f32_16x16x32_bf16(
                    af[i], bfr[j], acc[i][j], 0, 0, 0);
    }

    if (tid < 128) rsum[tid] = 0.f;
    __syncthreads();

    float s = sigma[0];
    float inv2s2 = 1.0f / (2.0f * s * s);
    #pragma unroll
    for (int i = 0; i < 2; ++i) {
        int lrow = wm + i * 16 + quad * 4;
        int rb = i0 + lrow;
        float rs0 = 0.f, rs1 = 0.f, rs2 = 0.f, rs3 = 0.f;
        #pragma unroll
        for (int j = 0; j < 4; ++j) {
            int c = j0 + wn + j * 16 + l16;
            float sqc = SQ[c];
            f32x4 v = acc[i][j];
            float av[4];
            #pragma unroll
            for (int r4 = 0; r4 < 4; ++r4) {
                int r = rb + r4;
                float d = fmaxf(SQ[r] + sqc - 2.0f * v[r4], 0.0f);
                unsigned short a = (r == c) ? (unsigned short)0
                                            : f2bf(__expf(-d * inv2s2));
                Ab[(long)r * Nn + c] = a;
                av[r4] = bf2f(a);
            }
            rs0 += av[0]; rs1 += av[1]; rs2 += av[2]; rs3 += av[3];
        }
        #pragma unroll
        for (int m = 1; m < 16; m <<= 1) {
            rs0 += __shfl_xor(rs0, m);
            rs1 += __shfl_xor(rs1, m);
            rs2 += __shfl_xor(rs2, m);
            rs3 += __shfl_xor(rs3, m);
        }
        if (l16 == 0) {
            atomicAdd(&rsum[lrow + 0], rs0);
            atomicAdd(&rsum[lrow + 1], rs1);
            atomicAdd(&rsum[lrow + 2], rs2);
            atomicAdd(&rsum[lrow + 3], rs3);
        }
    }
    __syncthreads();
    if (tid < 128) atomicAdd(&w[(long)b * Nn + i0 + tid], rsum[tid]);
}

// ---------------- weight convert + transpose + zero w/v/m ----------
__global__ __launch_bounds__(256) void convert_weights(
    const float* __restrict__ Wrel0, const float* __restrict__ Wroot0,
    const float* __restrict__ Wrel1, const float* __restrict__ Wroot1,
    const float* __restrict__ Wg,
    unsigned short* __restrict__ T0, unsigned short* __restrict__ T1,
    unsigned short* __restrict__ T2, unsigned short* __restrict__ T3,
    unsigned short* __restrict__ TG,
    float* __restrict__ w, float* __restrict__ vm)
{
    int idx = blockIdx.x * 256 + threadIdx.x;   // total 278528
    if (idx >= 245760) { vm[idx - 245760] = 0.f; return; }   // v+m: 32768 floats
    if (idx >= 212992) { w[idx - 212992] = 0.f; return; }    // w: 32768 floats
    if (idx >= 196608) {                         // WgT: [128 out][128 in]
        int e = idx - 196608;
        int o = e >> 7, i = e & 127;
        TG[e] = f2bf(Wg[(long)i * 128 + o]);
        return;
    }
    const float* src; unsigned short* dst; int kin; int e;
    if      (idx <  32768) { src = Wrel0;  dst = T0; kin = 128; e = idx; }
    else if (idx <  65536) { src = Wroot0; dst = T1; kin = 128; e = idx - 32768; }
    else if (idx < 131072) { src = Wrel1;  dst = T2; kin = 256; e = idx - 65536; }
    else                   { src = Wroot1; dst = T3; kin = 256; e = idx - 131072; }
    int o = (kin == 128) ? (e >> 7) : (e >> 8);
    int i = e & (kin - 1);
    dst[e] = f2bf(src[(long)i * 256 + o]);      // conv out-dims are all 256
}

// ---------------- v[b][c] = sum_j w[b][j]*h2[b][j][c]; m[b][c] = sum_j h2[b][j][c] --
__global__ __launch_bounds__(256) void reduce_h2(
    const unsigned short* __restrict__ h2b, const float* __restrict__ w,
    float* __restrict__ v, float* __restrict__ m)
{
    int b = blockIdx.x;
    int jc = blockIdx.y;        // 0..7, 64 nodes each
    int c = threadIdx.x;        // 0..255
    const unsigned short* H = h2b + ((long)b * Nn + jc * 64) * Hh + c;
    const float* wp = w + (long)b * Nn + jc * 64;
    float vp = 0.f, mp = 0.f;
    #pragma unroll 4
    for (int j = 0; j < 64; ++j) {
        float val = bf2f(H[(long)j * Hh]);
        mp += val;
        vp += wp[j] * val;
    }
    atomicAdd(&v[b * Hh + c], vp);
    atomicAdd(&m[b * Hh + c], mp);
}

// ---------------- head: layer2-collapse + mean + MLP ----------------
// g = (v/N)@Wrel2 + (m/N)@Wroot2 + brel2;  out = relu(g@W1+b1)@Wout + bout
__global__ __launch_bounds__(256) void head_kernel(
    const float* __restrict__ v, const float* __restrict__ m,
    const float* __restrict__ Wrel2, const float* __restrict__ Wroot2,
    const float* __restrict__ brel2,
    const float* __restrict__ W1, const float* __restrict__ b1,
    const float* __restrict__ Wout, const float* __restrict__ bout,
    float* __restrict__ out)
{
    int b = blockIdx.x;
    int j = threadIdx.x;
    __shared__ float vs[Hh], ms[Hh], gs[Hh], g2[Hh];
    vs[j] = v[b * Hh + j] * (1.0f / (float)Nn);
    ms[j] = m[b * Hh + j] * (1.0f / (float)Nn);
    __syncthreads();
    float s = brel2[j];
    for (int c = 0; c < Hh; ++c)
        s += vs[c] * Wrel2[c * Hh + j] + ms[c] * Wroot2[c * Hh + j];
    gs[j] = s;
    __syncthreads();
    float t = b1[j];
    for (int k = 0; k < Hh; ++k) t += gs[k] * W1[k * Hh + j];
    g2[j] = fmaxf(t, 0.f);
    __syncthreads();
    if (j < OUTD) {
        float s2 = bout[j];
        for (int k = 0; k < Hh; ++k) s2 += g2[k] * Wout[k * OUTD + j];
        out[b * OUTD + j] = s2;
    }
}

extern "C" void kernel_launch(void* const* d_in, const int* in_sizes, int n_in,
                              void* d_out, int out_size, void* d_ws, size_t ws_size,
                              hipStream_t stream) {
    const float* x      = (const float*)d_in[0];
    const float* sigma  = (const float*)d_in[4];
    const float* Wg     = (const float*)d_in[5];
    const float* bg     = (const float*)d_in[6];
    const float* Wrel0  = (const float*)d_in[7];
    const float* Wroot0 = (const float*)d_in[8];
    const float* brel0  = (const float*)d_in[9];
    const float* Wrel1  = (const float*)d_in[10];
    const float* Wroot1 = (const float*)d_in[11];
    const float* brel1  = (const float*)d_in[12];
    const float* Wrel2  = (const float*)d_in[13];
    const float* Wroot2 = (const float*)d_in[14];
    const float* brel2  = (const float*)d_in[15];
    const float* W1     = (const float*)d_in[16];
    const float* b1     = (const float*)d_in[17];
    const float* Wout   = (const float*)d_in[18];
    const float* bout   = (const float*)d_in[19];
    float* out = (float*)d_out;

    // Workspace layout (bytes)
    char* ws = (char*)d_ws;
    unsigned short* WgT  = (unsigned short*)(ws + 0);              // 32 KB
    unsigned short* h0b  = (unsigned short*)(ws + 16777216);       // 8 MB
    unsigned short* h0T  = (unsigned short*)(ws + 25165824);       // 8 MB
    float*          sq   = (float*)(ws + 33554432);                // 128 KB
    unsigned short* Aadj = (unsigned short*)(ws + 33685504);       // 32 MB
    unsigned short* agg  = (unsigned short*)(ws + 67239936);       // 16 MB
    unsigned short* h1b  = (unsigned short*)(ws + 84017152);       // 16 MB
    unsigned short* h1T  = (unsigned short*)(ws + 100794368);      // 16 MB
    unsigned short* h2b  = (unsigned short*)(ws + 117571584);      // 16 MB
    unsigned short* WrelT0  = (unsigned short*)(ws + 167903232);   // 64 KB
    unsigned short* WrootT0 = (unsigned short*)(ws + 167968768);   // 64 KB
    unsigned short* WrelT1  = (unsigned short*)(ws + 168034304);   // 128 KB
    unsigned short* WrootT1 = (unsigned short*)(ws + 168165376);   // 128 KB
    float*          w    = (float*)(ws + 168558592);               // 128 KB (A row sums)
    float*          v    = (float*)(ws + 168689664);               // 64 KB
    float*          m    = (float*)(ws + 168755200);               // 64 KB

    // weights -> bf16 transposed + zero w/v/m
    convert_weights<<<1088, 256, 0, stream>>>(Wrel0, Wroot0, Wrel1, Wroot1, Wg,
                                              WrelT0, WrootT0, WrelT1, WrootT1, WgT,
                                              w, v /* vm base: v then m contiguous */);

    // h0 (bf16 MFMA), writes node-major + transposed + row sumsq
    h0_mfma<<<dim3(MTOT / 128, 1, 1), 256, 0, stream>>>(x, WgT, bg, h0b, h0T, sq);

    // A = exp(-dist/(2 sigma^2)), zero diag; accumulate row sums w (XCD-swizzled 1D)
    gram_A_mfma<<<dim3(16 * Bsz, 1, 1), 512, 0, stream>>>(h0b, sq, sigma, Aadj, w);

    // ---- layer 0 ----
    gemm_bf16<<<dim3(4 * Bsz, 1, 1), 512, 0, stream>>>(
        Aadj, h0T, nullptr, nullptr, nullptr, agg, nullptr,
        Nn, Ff, Nn, 0,
        (long)Nn * Nn, (long)Ff * Nn, (long)Nn * Ff, 8);
    gemm_bf16<<<dim3(MTOT / 128, Hh / 128, 1), 512, 0, stream>>>(
        agg, WrelT0, h0b, WrootT0, brel0, h1b, h1T,
        MTOT, Hh, Ff, Ff, 0, 0, 0, 1);

    // ---- layer 1 ----
    gemm_bf16<<<dim3(8 * Bsz, 1, 1), 512, 0, stream>>>(
        Aadj, h1T, nullptr, nullptr, nullptr, agg, nullptr,
        Nn, Hh, Nn, 0,
        (long)Nn * Nn, (long)Hh * Nn, (long)Nn * Hh, 8);
    gemm_bf16<<<dim3(MTOT / 128, Hh / 128, 1), 512, 0, stream>>>(
        agg, WrelT1, h1b, WrootT1, brel1, h2b, nullptr,
        MTOT, Hh, Hh, Hh, 0, 0, 0, 1);

    // ---- layer 2 collapsed: v = w@h2, m = colsum(h2) ----
    reduce_h2<<<dim3(Bsz, 8), 256, 0, stream>>>(h2b, w, v, m);

    // head (layer-2 projection + mean + 2-layer MLP, fp32)
    head_kernel<<<Bsz, 256, 0, stream>>>(v, m, Wrel2, Wroot2, brel2,
                                         W1, b1, Wout, bout, out);
}